// Round 1
// baseline (1069.171 us; speedup 1.0000x reference)
//
#include <hip/hip_runtime.h>
#include <hip/hip_bf16.h>

// ---------------- constants ----------------
#define B_    16
#define SL_   512
#define S_    511
#define E_    256
#define NH_   4
#define I_    512
#define DHM_  128
#define DHS_  64
#define F_    384
#define NP_   8192               // padded row count (multiple of 64)
#define NROW  (B_*S_)            // 8176 real rows
#define EPS_  1e-5f

typedef __hip_bfloat16 bf16;
typedef __bf16 bf16x8v __attribute__((ext_vector_type(8)));
typedef float  f32x4v  __attribute__((ext_vector_type(4)));

__device__ __forceinline__ float rcp_(float x){ return __builtin_amdgcn_rcpf(x); }
__device__ __forceinline__ float sig_(float x){ return rcp_(1.f+__expf(-x)); }
__device__ __forceinline__ float silu_(float x){ return x*sig_(x); }
__device__ __forceinline__ float logsig_(float x){ return fminf(x,0.f) - __logf(1.f + __expf(-fabsf(x))); }
__device__ __forceinline__ float expneg_(float x){ return __expf(fminf(x,0.f)); }
__device__ __forceinline__ float expclamp_(float x){ return __expf(fminf(fmaxf(x,-80.f),80.f)); }
__device__ __forceinline__ float tanh_(float x){ return 1.f - 2.f*rcp_(__expf(2.f*x)+1.f); }

// ---------------- f32 -> bf16 weight conversion ----------------
__global__ __launch_bounds__(256) void k_cvt16(const float* __restrict__ src, bf16* __restrict__ dst, int n){
  int i=blockIdx.x*256+threadIdx.x;
  if(i<n) dst[i]=__float2bfloat16(src[i]);
}
// ---------------- f32 -> split bf16 (hi+lo) conversion ----------------
__global__ __launch_bounds__(256) void k_cvtsplit(const float* __restrict__ src,
  bf16* __restrict__ hi, bf16* __restrict__ lo, int n){
  int i=blockIdx.x*256+threadIdx.x;
  if(i<n){
    float v=src[i];
    bf16 h=__float2bfloat16(v);
    hi[i]=h;
    lo[i]=__float2bfloat16(v-__bfloat162float(h));
  }
}
// ---------------- transpose s_gate_w's inner 64x64 blocks: dst[blk][d][e]=src[blk][e][d] ----------------
__global__ __launch_bounds__(256) void k_wtrans(const float* __restrict__ src, float* __restrict__ dst){
  int i = blockIdx.x*256+threadIdx.x;   // over 16*64*64
  int blk = i>>12;
  int d = (i>>6)&63;
  int e = i&63;
  dst[(size_t)(blk*64+d)*64+e] = src[(size_t)(blk*64+e)*64+d];
}

// ---------------- build B-fragments of s_rec_w for the MFMA scan ----------------
// frag index f = t*2+kf  (t = N-tile 0..15 over cols [g][e], kf = K-half)
// lane l, elem j holds W[g][n][d][e] with col = 16t + (l&15) -> g=t>>2, e=(t&3)*16+(l&15),
// d = kf*32 + (l>>4)*8 + j.  Layout: wf[ (((n*16+t)*2+kf)*64 + l)*8 + j ]
__global__ __launch_bounds__(256) void k_wfrag(const float* __restrict__ rw, bf16* __restrict__ wf){
  int i = blockIdx.x*256+threadIdx.x;   // 4*16*2*64*8 = 65536
  int j  = i&7;
  int l  = (i>>3)&63;
  int kf = (i>>9)&1;
  int t  = (i>>10)&15;
  int n  = i>>14;
  int g = t>>2;
  int e = (t&3)*16 + (l&15);
  int d = kf*32 + (l>>4)*8 + j;
  wf[i] = __float2bfloat16(rw[((size_t)((g*4+n)*64 + d))*64 + e]);
}

// ---------------- embedding gather + fused LN0 -> split bf16 ----------------
__global__ __launch_bounds__(256) void k_embed(
  const int* __restrict__ questions, const int* __restrict__ responses, const int* __restrict__ skills,
  const float* __restrict__ q_embed, const float* __restrict__ qa_embed,
  const float* __restrict__ q_embed_diff, const float* __restrict__ qa_embed_diff,
  const float* __restrict__ difficult_param, const float* __restrict__ ln0w,
  float* __restrict__ x, float* __restrict__ qe,
  bf16* __restrict__ h_hi, bf16* __restrict__ h_lo,
  float* __restrict__ pide, int* __restrict__ tgt, int* __restrict__ qsh)
{
  __shared__ float red[256];
  int r = blockIdx.x; int e = threadIdx.x;
  float xa = 0.f;
  if (r < NROW){
    int b = r / S_, s = r % S_;
    int pid  = questions[b*SL_+s];
    int qd   = skills[b*SL_+s];
    int resp = responses[b*SL_+s];
    int t    = (resp > -1) ? resp : 0;
    float pe = difficult_param[pid];
    float q0 = q_embed[qd*E_+e];
    xa = q0 + qa_embed[t*E_+e] + pe*qa_embed_diff[t*E_+e];
    float qn = q0 + pe*q_embed_diff[qd*E_+e];
    x[(size_t)r*E_+e]=xa; qe[(size_t)r*E_+e]=qn;
    if (e==0){ pide[r]=pe; tgt[r]=t; qsh[r]=skills[b*SL_+s+1]; }
  } else {
    x[(size_t)r*E_+e]=0.f; qe[(size_t)r*E_+e]=0.f;
    if (e==0){ pide[r]=0.f; tgt[r]=-7; qsh[r]=0; }
  }
  red[e]=xa; __syncthreads();
  for(int s2=128;s2>0;s2>>=1){ if(e<s2) red[e]+=red[e+s2]; __syncthreads(); }
  float mu = red[0]*(1.f/E_); __syncthreads();
  float d = xa-mu;
  red[e]=d*d; __syncthreads();
  for(int s2=128;s2>0;s2>>=1){ if(e<s2) red[e]+=red[e+s2]; __syncthreads(); }
  float var = red[0]*(1.f/E_);
  float o = d*rsqrtf(var+EPS_)*ln0w[e];
  bf16 hv = __float2bfloat16(o);
  h_hi[(size_t)r*E_+e] = hv;
  h_lo[(size_t)r*E_+e] = __float2bfloat16(o-__bfloat162float(hv));
}

// ---------------- layernorm over E=256 (used for ln1) ----------------
__global__ __launch_bounds__(256) void k_ln(
  const float* __restrict__ in, const float* __restrict__ w, float* __restrict__ out)
{
  __shared__ float red[256];
  int r = blockIdx.x, t = threadIdx.x;
  float v = in[(size_t)r*E_+t];
  red[t]=v; __syncthreads();
  for(int s=128;s>0;s>>=1){ if(t<s) red[t]+=red[t+s]; __syncthreads(); }
  float mu = red[0]*(1.f/E_); __syncthreads();
  float d = v-mu;
  red[t]=d*d; __syncthreads();
  for(int s=128;s>0;s>>=1){ if(t<s) red[t]+=red[t+s]; __syncthreads(); }
  float var = red[0]*(1.f/E_);
  out[(size_t)r*E_+t] = d*rsqrtf(var+EPS_)*w[t];
}

// ---------------- split-bf16 MFMA GEMM: C = (Ah+Al)(Bh+Bl)^T + bias (drop lo*lo) ----------------
__global__ __launch_bounds__(256) void k_gemm16s(
  const bf16* __restrict__ Ah, const bf16* __restrict__ Al,
  const bf16* __restrict__ Bh, const bf16* __restrict__ Bl,
  const float* __restrict__ bias, float* __restrict__ C, int M, int K)
{
  int tid=threadIdx.x;
  int wave=tid>>6, lane=tid&63;
  int wr=wave>>1, wc=wave&1;
  int row0=blockIdx.y*64 + wr*32;
  int col0=blockIdx.x*64 + wc*32;
  int lrow = lane&15, lq = lane>>4;
  f32x4v acc[2][2] = {};
  size_t aoff = (size_t)(row0+lrow)*K + lq*8;
  size_t boff = (size_t)(col0+lrow)*K + lq*8;
  for(int k0=0;k0<K;k0+=32){
    bf16x8v ah0=*(const bf16x8v*)(Ah+aoff+k0), ah1=*(const bf16x8v*)(Ah+aoff+(size_t)16*K+k0);
    bf16x8v al0=*(const bf16x8v*)(Al+aoff+k0), al1=*(const bf16x8v*)(Al+aoff+(size_t)16*K+k0);
    bf16x8v bh0=*(const bf16x8v*)(Bh+boff+k0), bh1=*(const bf16x8v*)(Bh+boff+(size_t)16*K+k0);
    bf16x8v bl0=*(const bf16x8v*)(Bl+boff+k0), bl1=*(const bf16x8v*)(Bl+boff+(size_t)16*K+k0);
    acc[0][0]=__builtin_amdgcn_mfma_f32_16x16x32_bf16(ah0,bh0,acc[0][0],0,0,0);
    acc[0][1]=__builtin_amdgcn_mfma_f32_16x16x32_bf16(ah0,bh1,acc[0][1],0,0,0);
    acc[1][0]=__builtin_amdgcn_mfma_f32_16x16x32_bf16(ah1,bh0,acc[1][0],0,0,0);
    acc[1][1]=__builtin_amdgcn_mfma_f32_16x16x32_bf16(ah1,bh1,acc[1][1],0,0,0);
    acc[0][0]=__builtin_amdgcn_mfma_f32_16x16x32_bf16(ah0,bl0,acc[0][0],0,0,0);
    acc[0][1]=__builtin_amdgcn_mfma_f32_16x16x32_bf16(ah0,bl1,acc[0][1],0,0,0);
    acc[1][0]=__builtin_amdgcn_mfma_f32_16x16x32_bf16(ah1,bl0,acc[1][0],0,0,0);
    acc[1][1]=__builtin_amdgcn_mfma_f32_16x16x32_bf16(ah1,bl1,acc[1][1],0,0,0);
    acc[0][0]=__builtin_amdgcn_mfma_f32_16x16x32_bf16(al0,bh0,acc[0][0],0,0,0);
    acc[0][1]=__builtin_amdgcn_mfma_f32_16x16x32_bf16(al0,bh1,acc[0][1],0,0,0);
    acc[1][0]=__builtin_amdgcn_mfma_f32_16x16x32_bf16(al1,bh0,acc[1][0],0,0,0);
    acc[1][1]=__builtin_amdgcn_mfma_f32_16x16x32_bf16(al1,bh1,acc[1][1],0,0,0);
  }
  #pragma unroll
  for(int mi=0;mi<2;mi++){
    #pragma unroll
    for(int ni=0;ni<2;ni++){
      #pragma unroll
      for(int r=0;r<4;r++){
        int row=row0+mi*16+lq*4+r;
        int col=col0+ni*16+lrow;
        C[(size_t)row*M+col]=acc[mi][ni][r] + bias[col];
      }
    }
  }
}

// ---------------- bf16 MFMA GEMM (+ optional residual) ----------------
__global__ __launch_bounds__(256) void k_gemm16(
  const bf16* __restrict__ A, const bf16* __restrict__ Bw,
  const float* __restrict__ bias, const float* __restrict__ resid,
  float* __restrict__ C, bf16* __restrict__ C16,
  int M, int K, int relu)
{
  int tid=threadIdx.x;
  int wave=tid>>6, lane=tid&63;
  int wr=wave>>1, wc=wave&1;
  int row0=blockIdx.y*64 + wr*32;
  int col0=blockIdx.x*64 + wc*32;
  int lrow = lane&15, lq = lane>>4;
  f32x4v acc[2][2] = {};
  const bf16* Abase = A  + (size_t)(row0+lrow)*K + lq*8;
  const bf16* Bbase = Bw + (size_t)(col0+lrow)*K + lq*8;
  for(int k0=0;k0<K;k0+=32){
    bf16x8v a0 = *(const bf16x8v*)(Abase + k0);
    bf16x8v a1 = *(const bf16x8v*)(Abase + (size_t)16*K + k0);
    bf16x8v b0 = *(const bf16x8v*)(Bbase + k0);
    bf16x8v b1 = *(const bf16x8v*)(Bbase + (size_t)16*K + k0);
    acc[0][0]=__builtin_amdgcn_mfma_f32_16x16x32_bf16(a0,b0,acc[0][0],0,0,0);
    acc[0][1]=__builtin_amdgcn_mfma_f32_16x16x32_bf16(a0,b1,acc[0][1],0,0,0);
    acc[1][0]=__builtin_amdgcn_mfma_f32_16x16x32_bf16(a1,b0,acc[1][0],0,0,0);
    acc[1][1]=__builtin_amdgcn_mfma_f32_16x16x32_bf16(a1,b1,acc[1][1],0,0,0);
  }
  #pragma unroll
  for(int mi=0;mi<2;mi++){
    #pragma unroll
    for(int ni=0;ni<2;ni++){
      #pragma unroll
      for(int r=0;r<4;r++){
        int row=row0+mi*16+lq*4+r;       // C/D: col=lane&15, row=(lane>>4)*4+reg  [m89]
        int col=col0+ni*16+lrow;
        float v=acc[mi][ni][r] + (bias? bias[col]:0.f);
        if(relu) v=fmaxf(v,0.f);
        if(resid) v += resid[(size_t)row*M+col];
        if(C)   C[(size_t)row*M+col]=v;
        if(C16) C16[(size_t)row*M+col]=__float2bfloat16(v);
      }
    }
  }
}

// ---------------- causal depthwise conv K=4 + silu ----------------
__global__ __launch_bounds__(256) void k_conv_silu(
  const float* __restrict__ in, int ild, const float* __restrict__ w, const float* __restrict__ bws,
  float* __restrict__ out, int old_, int C)
{
  int i = blockIdx.x*256 + threadIdx.x;
  int r = i / C, c = i % C;
  if (r >= NP_) return;
  float acc = 0.f;
  if (r < NROW) {
    int b=r/S_, s=r%S_;
    acc = bws[c];
    #pragma unroll
    for(int j=0;j<4;j++){
      int ss=s-3+j;
      if(ss>=0) acc += w[c*4+j] * in[(size_t)(b*S_+ss)*ild + c];
    }
    acc = silu_(acc);
  }
  out[(size_t)r*old_ + c] = acc;
}

// ---------------- headwise 4x4 block projections q,k,v ----------------
__global__ __launch_bounds__(256) void k_headwise(
  const float* __restrict__ xc, const float* __restrict__ xm, int xmld,
  const float* __restrict__ wq, const float* __restrict__ wk, const float* __restrict__ wv,
  float* __restrict__ q, float* __restrict__ k, float* __restrict__ v)
{
  int i=blockIdx.x*256+threadIdx.x;
  int r=i/I_, c=i%I_;
  if(r>=NP_) return;
  size_t oi=(size_t)r*I_+c;
  if(r>=NROW){ q[oi]=0.f; k[oi]=0.f; v[oi]=0.f; return; }
  int n=c>>2, o=c&3;
  const float* xcr = xc + (size_t)r*I_ + n*4;
  const float* xmr = xm + (size_t)r*xmld + n*4;
  float aq=0.f, ak=0.f, av=0.f;
  #pragma unroll
  for(int d=0;d<4;d++){
    float xcv=xcr[d], xmv=xmr[d];
    aq += xcv*wq[(n*4+o)*4+d];
    ak += xcv*wk[(n*4+o)*4+d];
    av += xmv*wv[(n*4+o)*4+d];
  }
  q[oi]=aq; k[oi]=ak; v[oi]=av;
}

// ---------------- ig/fg gates ----------------
__global__ __launch_bounds__(256) void k_igfg(
  const float* __restrict__ q, const float* __restrict__ k, const float* __restrict__ v,
  const float* __restrict__ wig, const float* __restrict__ big,
  const float* __restrict__ wfg, const float* __restrict__ bfg,
  float* __restrict__ igb, float* __restrict__ fgb)
{
  int r=blockIdx.x;
  int wid=threadIdx.x>>6, lane=threadIdx.x&63;
  int b=r/S_, s=r%S_;
  for(int c=wid; c<8; c+=4){
    int h=c>>1; int isfg=c&1;
    const float* w = isfg? wfg : wig;
    float acc=0.f;
    for(int f=lane; f<1536; f+=64){
      float val = (f<512)? q[(size_t)r*512+f]
                : (f<1024)? k[(size_t)r*512+f-512]
                : v[(size_t)r*512+f-1024];
      acc += val*w[h*1536+f];
    }
    for(int m=32;m;m>>=1) acc+=__shfl_xor(acc,m,64);
    if(lane==0){
      if(isfg) fgb[(b*4+h)*512+s]=acc+bfg[h];
      else     igb[(b*4+h)*512+s]=acc+big[h];
    }
  }
}

// ---------------- decay prep (parallel scans): one block per bh ----------------
__global__ __launch_bounds__(256) void k_decay(
  const float* __restrict__ igb, const float* __restrict__ fgb,
  float* __restrict__ cs1, float* __restrict__ g, float* __restrict__ M)
{
  int bh = blockIdx.x; int tid = threadIdx.x;
  __shared__ float buf[512];
  __shared__ float buf2[512];
  for (int s=tid; s<512; s+=256)
    buf[s] = (s<S_) ? logsig_(fgb[bh*512+s]) : 0.f;
  __syncthreads();
  for (int off=1; off<512; off<<=1){
    int s0=tid, s1=tid+256;
    float v0 = buf[s0] + ((s0>=off)? buf[s0-off] : 0.f);
    float v1 = buf[s1] + ((s1>=off)? buf[s1-off] : 0.f);
    __syncthreads();
    buf[s0]=v0; buf[s1]=v1;
    __syncthreads();
  }
  for (int s=tid; s<512; s+=256){
    float c = buf[s];
    if (s<S_){
      cs1[bh*512+s]=c;
      float gv = igb[bh*512+s]-c;
      g[bh*512+s]=gv;
      buf2[s]=gv;
    } else buf2[s] = -3.4e38f;
  }
  __syncthreads();
  for (int off=1; off<512; off<<=1){
    int s0=tid, s1=tid+256;
    float v0 = fmaxf(buf2[s0], (s0>=off)? buf2[s0-off] : -3.4e38f);
    float v1 = fmaxf(buf2[s1], (s1>=off)? buf2[s1-off] : -3.4e38f);
    __syncthreads();
    buf2[s0]=v0; buf2[s1]=v1;
    __syncthreads();
  }
  for (int s=tid; s<S_; s+=256) M[bh*512+s] = buf2[s];
}

// ---------------- tiled attention ----------------
#define TQ 32
#define TS 32
__global__ __launch_bounds__(256) void k_attn(
  const float* __restrict__ q, const float* __restrict__ k, const float* __restrict__ v,
  const float* __restrict__ cs1, const float* __restrict__ g, const float* __restrict__ M,
  const float* __restrict__ onw, float* __restrict__ hflat)
{
  __shared__ __align__(16) float qs[TQ][132];
  __shared__ __align__(16) float ks[TS][132];
  __shared__ __align__(16) float vs[TS][128];
  __shared__ float Sw[TQ][33];
  __shared__ float MtS[TQ], cssS[TQ], lsumS[TQ], gsS[TS];
  int tq = blockIdx.x, bh = blockIdx.y;
  int b = bh>>2, h = bh&3;
  int tid = threadIdx.x;
  int i = tid>>4, j = tid&15;
  int t0 = tq*TQ;
  {
    int row = tid>>3, c4 = (tid&7)*4;
    const float4* src = (const float4*)(q + (size_t)(b*S_ + t0 + row)*512 + h*128);
    float4* dst = (float4*)&qs[row][0];
    #pragma unroll
    for(int c=0;c<4;c++) dst[c4+c] = src[c4+c];
  }
  if (tid < TQ){
    int t = t0 + tid; int tc = (t<S_)? t : (S_-1);
    MtS[tid]  = M[bh*512 + tc];
    cssS[tid] = cs1[bh*512 + tc];
    lsumS[tid]= 0.f;
  }
  float o[2][8] = {};
  int t1 = min(t0+TQ, S_);
  int nst = (t1 + TS - 1)/TS;
  const float sc = 0.08838834764831843f;
  for (int st=0; st<nst; ++st){
    int s0 = st*TS;
    __syncthreads();
    {
      int row = tid>>3, c4 = (tid&7)*4;
      const float4* srck = (const float4*)(k + (size_t)(b*S_ + s0 + row)*512 + h*128);
      const float4* srcv = (const float4*)(v + (size_t)(b*S_ + s0 + row)*512 + h*128);
      float4* dk = (float4*)&ks[row][0];
      float4* dv = (float4*)&vs[row][0];
      #pragma unroll
      for(int c=0;c<4;c++){ dk[c4+c]=srck[c4+c]; dv[c4+c]=srcv[c4+c]; }
      if (tid < TS) gsS[tid] = g[bh*512 + s0 + tid];
    }
    __syncthreads();
    float a00=0,a01=0,a10=0,a11=0;
    {
      const float4* q0 = (const float4*)&qs[i*2][0];
      const float4* q1 = (const float4*)&qs[i*2+1][0];
      const float4* k0 = (const float4*)&ks[j][0];
      const float4* k1 = (const float4*)&ks[j+16][0];
      #pragma unroll
      for(int d4=0; d4<32; ++d4){
        float4 qa=q0[d4], qb=q1[d4], ka=k0[d4], kb=k1[d4];
        a00 += qa.x*ka.x+qa.y*ka.y+qa.z*ka.z+qa.w*ka.w;
        a01 += qa.x*kb.x+qa.y*kb.y+qa.z*kb.z+qa.w*kb.w;
        a10 += qb.x*ka.x+qb.y*ka.y+qb.z*ka.z+qb.w*ka.w;
        a11 += qb.x*kb.x+qb.y*kb.y+qb.z*kb.z+qb.w*kb.w;
      }
    }
    int tA = t0 + i*2, tB = tA+1;
    int sA = s0 + j,   sB = sA + 16;
    float gA = gsS[j], gB = gsS[j+16];
    float mA = MtS[i*2], mB = MtS[i*2+1];
    float w00 = (sA<=tA)? a00*sc*expneg_(gA-mA) : 0.f;
    float w01 = (sB<=tA)? a01*sc*expneg_(gB-mA) : 0.f;
    float w10 = (sA<=tB)? a10*sc*expneg_(gA-mB) : 0.f;
    float w11 = (sB<=tB)? a11*sc*expneg_(gB-mB) : 0.f;
    float r0 = w00+w01, r1 = w10+w11;
    #pragma unroll
    for(int msk=1; msk<16; msk<<=1){ r0 += __shfl_xor(r0,msk,16); r1 += __shfl_xor(r1,msk,16); }
    if (j==0){ lsumS[i*2] += r0; lsumS[i*2+1] += r1; }
    Sw[i*2][j]     = w00; Sw[i*2][j+16]   = w01;
    Sw[i*2+1][j]   = w10; Sw[i*2+1][j+16] = w11;
    __syncthreads();
    #pragma unroll 8
    for(int s=0;s<TS;s++){
      float w0 = Sw[i*2][s], w1 = Sw[i*2+1][s];
      float4 v0 = *(const float4*)&vs[s][j*4];
      float4 v1 = *(const float4*)&vs[s][64+j*4];
      o[0][0]+=w0*v0.x; o[0][1]+=w0*v0.y; o[0][2]+=w0*v0.z; o[0][3]+=w0*v0.w;
      o[0][4]+=w0*v1.x; o[0][5]+=w0*v1.y; o[0][6]+=w0*v1.z; o[0][7]+=w0*v1.w;
      o[1][0]+=w1*v0.x; o[1][1]+=w1*v0.y; o[1][2]+=w1*v0.z; o[1][3]+=w1*v0.w;
      o[1][4]+=w1*v1.x; o[1][5]+=w1*v1.y; o[1][6]+=w1*v1.z; o[1][7]+=w1*v1.w;
    }
  }
  __syncthreads();
  #pragma unroll
  for(int r=0;r<2;r++){
    int tl = i*2+r;
    int t = t0 + tl;
    float maxD = cssS[tl] + MtS[tl];
    float norm = fmaxf(fabsf(lsumS[tl]), expclamp_(-maxD));
    float scale = rcp_(norm+1e-6f);
    float sum=0.f;
    #pragma unroll
    for(int d=0;d<8;d++){ o[r][d]*=scale; sum+=o[r][d]; }
    #pragma unroll
    for(int msk=1; msk<16; msk<<=1) sum += __shfl_xor(sum,msk,16);
    float mu = sum*(1.f/128.f);
    float var=0.f;
    #pragma unroll
    for(int d=0;d<8;d++){ float dd=o[r][d]-mu; var+=dd*dd; }
    #pragma unroll
    for(int msk=1; msk<16; msk<<=1) var += __shfl_xor(var,msk,16);
    float rs = rsqrtf(var*(1.f/128.f)+EPS_);
    if (t < S_){
      float* dst = hflat + (size_t)(b*S_+t)*1024 + h*128;
      #pragma unroll
      for(int c=0;c<4;c++) dst[j*4+c]    = (o[r][c]  -mu)*rs*onw[h*128+j*4+c];
      #pragma unroll
      for(int c=0;c<4;c++) dst[64+j*4+c] = (o[r][4+c]-mu)*rs*onw[h*128+64+j*4+c];
    }
  }
}

// ---------------- hout = (hflat + skip*xc) * silu(z) -> bf16 ----------------
__global__ __launch_bounds__(256) void k_hout(
  const float* __restrict__ A, const float* __restrict__ xc, const float* __restrict__ skip,
  bf16* __restrict__ out16)
{
  int i=blockIdx.x*256+threadIdx.x;
  int r=i/512, c=i%512;
  float hf=A[(size_t)r*1024+c];
  float z =A[(size_t)r*1024+512+c];
  out16[(size_t)r*512+c] = __float2bfloat16((hf + skip[c]*xc[(size_t)r*512+c]) * silu_(z));
}

// ---------------- wx: tiled, transposed weights in registers (coalesced), h-tile in LDS ----------------
// gwT layout: gwT[((g*4+n)*64+d)*64+e] == s_gate_w[g][n][e][d]
#define WXR 64
__global__ __launch_bounds__(256,2) void k_wx(
  const float* __restrict__ h, const float* __restrict__ hc,
  const float* __restrict__ gwT, const float* __restrict__ gb,
  float* __restrict__ wx)
{
  int rt = blockIdx.x, g = blockIdx.y;
  int tid = threadIdx.x;
  int n = tid>>6, e = tid&63;
  const float* src = (g<2)? hc : h;
  __shared__ __align__(16) float hs[WXR][260];
  float W[64];
  #pragma unroll
  for(int d=0;d<64;d++) W[d] = gwT[(size_t)(((g*4+n)*64+d))*64 + e];  // = w[g][n][e][d], lane-coalesced
  float bias = gb[(g*4+n)*64+e];
  int row0 = rt*WXR;
  for(int idx=tid; idx<WXR*64; idx+=256){
    int rr = idx>>6, cc4 = (idx&63)*4;
    *(float4*)&hs[rr][cc4] = *(const float4*)(src + (size_t)(row0+rr)*256 + cc4);
  }
  __syncthreads();
  #pragma unroll 4
  for(int rr=0; rr<WXR; ++rr){
    int r = row0+rr;
    if (r>=NROW) break;
    const float* hrow = &hs[rr][n*64];
    float a0=0,a1=0,a2=0,a3=0;
    #pragma unroll
    for(int d=0;d<64;d+=4){
      float4 hv = *(const float4*)&hrow[d];   // wave-uniform address -> LDS broadcast
      a0+=hv.x*W[d]; a1+=hv.y*W[d+1]; a2+=hv.z*W[d+2]; a3+=hv.w*W[d+3];
    }
    int b=r/S_, s=r%S_;
    wx[((size_t)(b*4+n)*512 + s)*256 + g*64 + e] = bias + ((a0+a1)+(a2+a3));
  }
}

// ---------------- sLSTM scan: single wave per (b,n), MFMA recurrent matvec, zero barriers ----------------
// raw[g*64+e] = wx + y(1x64) @ W(64x256) done as 32x mfma_f32_16x16x32_bf16.
// A-fragment is built with ALL 16 M-rows identical (each lane-group reads the same y bytes via
// ds_bpermute), so every lane's C regs hold raw for cols == (lane&15) mod 16 across the 16 N-tiles.
// Lane l handles element e = l: raw[g][l] = acc[4g + (l>>4)][0] selected by 3 cndmasks.
__global__ __launch_bounds__(64,1) void k_scan(
  const float* __restrict__ wx, const bf16* __restrict__ wf, float* __restrict__ y_out)
{
  int bn = blockIdx.x; int b = bn>>2, n = bn&3;
  int l = threadIdx.x;          // 0..63
  int q = l>>4;                 // lane group
  bool q1 = (q&1)!=0, q2 = (q&2)!=0;

  // resident B-fragments of W (32 frags x 16B/lane = 128 VGPR)
  bf16x8v Wf[32];
  const bf16* wbase = wf + (size_t)n*16384 + (size_t)l*8;
  #pragma unroll
  for(int f=0; f<32; f++) Wf[f] = *(const bf16x8v*)(wbase + (size_t)f*512);

  const float* wxBase = wx + (size_t)bn*512*256;
  float* yBase = y_out + (size_t)(b*S_)*256 + n*64 + l;

  // wx register prefetch pipeline, depth 4 (4 coalesced dwords/step)
  float4 w0,w1,w2,w3;
  {
    const float* r0=wxBase;         w0=make_float4(r0[l],r0[64+l],r0[128+l],r0[192+l]);
    const float* r1=wxBase+256;     w1=make_float4(r1[l],r1[64+l],r1[128+l],r1[192+l]);
    const float* r2=wxBase+512;     w2=make_float4(r2[l],r2[64+l],r2[128+l],r2[192+l]);
    const float* r3=wxBase+768;     w3=make_float4(r3[l],r3[64+l],r3[128+l],r3[192+l]);
  }

  // bpermute source addresses (bytes): frag0 word j pulls pair {y[8q+2j],y[8q+2j+1]} from lane 8q+2j
  int ab = q*32;

  union U8 { unsigned int w[4]; bf16x8v v; };
  U8 fa0, fa1;
  #pragma unroll
  for(int kk=0;kk<4;kk++){ fa0.w[kk]=0u; fa1.w[kk]=0u; }
  f32x4v z4 = {0.f,0.f,0.f,0.f};

  float c=0.f, nn=0.f, m=0.f;

  for (int s=0; s<S_; ++s){
    // 32 MFMAs: 16 N-tiles x (K=64 as two chained k-halves)
    f32x4v acc[16];
    bf16x8v a0 = fa0.v, a1 = fa1.v;
    #pragma unroll
    for(int t=0;t<16;t++){
      acc[t] = __builtin_amdgcn_mfma_f32_16x16x32_bf16(a0, Wf[2*t],   z4,     0,0,0);
      acc[t] = __builtin_amdgcn_mfma_f32_16x16x32_bf16(a1, Wf[2*t+1], acc[t], 0,0,0);
    }

    float4 wg = w0;
    // rotate prefetch pipeline; issue load for step s+4
    w0=w1; w1=w2; w2=w3;
    { int sp = s+4; if (sp>510) sp=510;
      const float* row = wxBase + (size_t)sp*256;
      w3 = make_float4(row[l], row[64+l], row[128+l], row[192+l]); }

    // extract raw[g][e=l]: tile t = 4g + q, reg 0 (all rows identical)
    float rg[4];
    #pragma unroll
    for(int g=0; g<4; g++){
      float v0=acc[4*g+0][0], v1=acc[4*g+1][0], v2=acc[4*g+2][0], v3=acc[4*g+3][0];
      float lo = q1? v1:v0;
      float hi = q1? v3:v2;
      rg[g] = q2? hi:lo;
    }
    float iraw=rg[0]+wg.x, fraw=rg[1]+wg.y, zraw=rg[2]+wg.z, oraw=rg[3]+wg.w;

    float lfm  = m + logsig_(fraw);
    float mnew = fmaxf(iraw, lfm);
    float ig = expneg_(iraw-mnew), fg = expneg_(lfm-mnew);
    c  = fg*c + ig*tanh_(zraw);
    nn = fmaxf(fg*nn + ig, 1e-30f);
    float y = sig_(oraw)*c*rcp_(nn);
    m = mnew;

    yBase[(size_t)s*256] = y;

    // marshal y -> next A-fragments: pack even/odd pairs, 8 ds_bpermute
    bf16 yb = __float2bfloat16(y);
    unsigned short hbits; __builtin_memcpy(&hbits,&yb,2);
    unsigned int u = hbits;
    unsigned int o = __shfl_xor(u, 1, 64);
    unsigned int pair = u | (o<<16);          // valid on even lanes (the bperm sources)
    #pragma unroll
    for(int j2=0;j2<4;j2++){
      fa0.w[j2] = (unsigned int)__builtin_amdgcn_ds_bpermute(ab + j2*8,        (int)pair);
      fa1.w[j2] = (unsigned int)__builtin_amdgcn_ds_bpermute(128 + ab + j2*8,  (int)pair);
    }
  }
}

// ---------------- yn-add + fused LN2 -> bf16 ----------------
__global__ __launch_bounds__(256) void k_ynadd_ln2(
  const float* __restrict__ y, const float* __restrict__ gn,
  float* __restrict__ x, const float* __restrict__ ln2w, bf16* __restrict__ h16)
{
  __shared__ float red[256];
  int r=blockIdx.x, t=threadIdx.x;
  float xv = x[(size_t)r*256+t];
  if (r < NROW){
    float v=y[(size_t)r*256+t];
    float s=v;
    for(int m=32;m;m>>=1) s+=__shfl_xor(s,m,64);
    float mu=s*(1.f/64.f);
    float d=v-mu;
    float q=d*d;
    for(int m=32;m;m>>=1) q+=__shfl_xor(q,m,64);
    float var=q*(1.f/64.f);
    xv += d*rsqrtf(var+EPS_)*gn[t];
    x[(size_t)r*256+t]=xv;
  }
  red[t]=xv; __syncthreads();
  for(int s=128;s>0;s>>=1){ if(t<s) red[t]+=red[t+s]; __syncthreads(); }
  float mu2=red[0]*(1.f/E_); __syncthreads();
  float dd=xv-mu2;
  red[t]=dd*dd; __syncthreads();
  for(int s=128;s>0;s>>=1){ if(t<s) red[t]+=red[t+s]; __syncthreads(); }
  float var2=red[0]*(1.f/E_);
  h16[(size_t)r*256+t]=__float2bfloat16(dd*rsqrtf(var2+EPS_)*ln2w[t]);
}

// ---------------- ffn gate: relu(gate)*upf -> bf16 ----------------
__global__ __launch_bounds__(256) void k_ffmul(const float* __restrict__ ffu, bf16* __restrict__ out)
{
  int i=blockIdx.x*256+threadIdx.x;
  int r=i/384, j=i%384;
  out[(size_t)r*384+j] = __float2bfloat16(fmaxf(ffu[(size_t)r*768+j],0.f)*ffu[(size_t)r*768+384+j]);
}

// ---------------- fused postnorm-LN + cq build -> bf16 ----------------
__global__ __launch_bounds__(256) void k_cq_ln(
  const float* __restrict__ x, const float* __restrict__ pw,
  const float* __restrict__ qe, const float* __restrict__ pide, const int* __restrict__ tgt,
  bf16* __restrict__ cq)
{
  __shared__ float red[256];
  int r=blockIdx.x, t=threadIdx.x;
  float v = x[(size_t)r*256+t];
  red[t]=v; __syncthreads();
  for(int s=128;s>0;s>>=1){ if(t<s) red[t]+=red[t+s]; __syncthreads(); }
  float mu=red[0]*(1.f/E_); __syncthreads();
  float d=v-mu;
  red[t]=d*d; __syncthreads();
  for(int s=128;s>0;s>>=1){ if(t<s) red[t]+=red[t+s]; __syncthreads(); }
  float var=red[0]*(1.f/E_);
  float dv = d*rsqrtf(var+EPS_)*pw[t];
  float pe=pide[r]; int tg=tgt[r];
  size_t base=(size_t)r*1024;
  cq[base+t]=__float2bfloat16(dv-pe);
  cq[base+256+t]=__float2bfloat16(qe[(size_t)r*256+t]);
  cq[base+512+t]=__float2bfloat16((tg==1)? dv:0.f);
  cq[base+768+t]=__float2bfloat16((tg==0)? dv:0.f);
}

// ---------------- final: selected logit + sigmoid ----------------
__global__ __launch_bounds__(256) void k_final(
  const float* __restrict__ o2, const float* __restrict__ w3, const float* __restrict__ b3,
  const int* __restrict__ qsh, float* __restrict__ out)
{
  __shared__ float red[256];
  int r=blockIdx.x, t=threadIdx.x;
  int qi=qsh[r];
  float p=o2[(size_t)r*256+t]*w3[(size_t)qi*256+t];
  red[t]=p; __syncthreads();
  for(int s=128;s>0;s>>=1){ if(t<s) red[t]+=red[t+s]; __syncthreads(); }
  if(t==0) out[r]=sig_(red[0]+b3[qi]);
}

// ---------------- launch ----------------
extern "C" void kernel_launch(void* const* d_in, const int* in_sizes, int n_in,
                              void* d_out, int out_size, void* d_ws, size_t ws_size,
                              hipStream_t stream) {
  const int* questions = (const int*)d_in[0];
  const int* responses = (const int*)d_in[1];
  const int* skills    = (const int*)d_in[2];
  const float* q_embed       = (const float*)d_in[4];
  const float* qa_embed      = (const float*)d_in[5];
  const float* q_embed_diff  = (const float*)d_in[6];
  const float* qa_embed_diff = (const float*)d_in[7];
  const float* difficult_param=(const float*)d_in[8];
  const float* ln0_w   = (const float*)d_in[9];
  const float* m_up_w  = (const float*)d_in[10];
  const float* m_up_b  = (const float*)d_in[11];
  const float* m_conv_w= (const float*)d_in[12];
  const float* m_conv_b= (const float*)d_in[13];
  const float* m_q_w   = (const float*)d_in[14];
  const float* m_k_w   = (const float*)d_in[15];
  const float* m_v_w   = (const float*)d_in[16];
  const float* m_ig_w  = (const float*)d_in[17];
  const float* m_ig_b  = (const float*)d_in[18];
  const float* m_fg_w  = (const float*)d_in[19];
  const float* m_fg_b  = (const float*)d_in[20];
  const float* m_outnorm_w=(const float*)d_in[21];
  const float* m_skip  = (const float*)d_in[22];
  const float* m_down_w= (const float*)d_in[23];
  const float* m_down_b= (const float*)d_in[24];
  const float* ln1_w   = (const float*)d_in[25];
  const float* s_conv_w= (const float*)d_in[26];
  const float* s_conv_b= (const float*)d_in[27];
  const float* s_gate_w= (const float*)d_in[28];
  const float* s_rec_w = (const float*)d_in[29];
  const float* s_bias  = (const float*)d_in[30];
  const float* s_gn_w  = (const float*)d_in[31];
  const float* ln2_w   = (const float*)d_in[32];
  const float* ffn_up_w= (const float*)d_in[33];
  const float* ffn_up_b= (const float*)d_in[34];
  const float* ffn_down_w=(const float*)d_in[35];
  const float* ffn_down_b=(const float*)d_in[36];
  const float* postnorm_w=(const float*)d_in[37];
  const float* out_w1  = (const float*)d_in[38];
  const float* out_b1  = (const float*)d_in[39];
  const float* out_w2  = (const float*)d_in[40];
  const float* out_b2  = (const float*)d_in[41];
  const float* out_w3  = (const float*)d_in[42];
  const float* out_b3  = (const float*)d_in[43];

  float* ws = (float*)d_ws;
  const size_t R = (size_t)NP_*256;
  float* x    = ws;
  float* qe   = ws + R;
  float* h    = ws + 2*R;
  float* t256 = ws + 3*R;        // early: split-bf16 LN0 output (h_hi/h_lo); late: out_w2 result
  float* A    = ws + 4*R;        // NP x 1024 ; also scan-layout wx
  float* Bb   = ws + 8*R;        // NP x 512
  float* Cb   = ws + 10*R;       // NP x 512  (q; later y_out; later b16)
  float* Db   = ws + 12*R;       // NP x 512  (k; later hout16 / ffg16)
  float* Eb   = ws + 14*R;       // NP x 512  (v; later cq16)
  float* pide = ws + 16*R;
  int*   tgt  = (int*)(ws + 16*R + NP_);
  int*   qsh  = (int*)(ws + 16*R + 2*NP_);
  float* igb  = ws + 16*R + 3*NP_;
  float* fgb  = igb + 64*512;
  float* cs1  = fgb + 64*512;
  float* gdec = cs1 + 64*512;
  float* Mrun = gdec + 64*512;
  bf16* wpool = (bf16*)(Mrun + 64*512);
  bf16* m_down_w16  = wpool;
  bf16* ffn_up_w16  = m_down_w16 + 256*512;
  bf16* ffn_down_w16= ffn_up_w16 + 768*256;
  bf16* out_w1_16   = ffn_down_w16 + 256*384;
  bf16* out_w2_16   = out_w1_16 + 512*1024;
  bf16* h16         = out_w2_16 + 256*512;
  bf16* m_up_whi    = h16 + (size_t)NP_*256;     // 1024*256
  bf16* m_up_wlo    = m_up_whi + 1024*256;       // 1024*256
  float* gwT        = (float*)(m_up_wlo + 1024*256);  // 16*64*64 floats (256 KB)
  bf16* wfrag       = (bf16*)(gwT + 16*64*64);   // 65536 bf16 (128 KB): MFMA B-frags of s_rec_w
  bf16* hout16 = (bf16*)Db;
  bf16* ffg16  = (bf16*)Db;
  bf16* cq16   = (bf16*)Eb;
  bf16* b16    = (bf16*)Cb;
  bf16* h_hi   = (bf16*)t256;                    // NP*256
  bf16* h_lo   = h_hi + (size_t)NP_*256;         // NP*256 (fits in t256's R floats)

  // ---- one-time weight conversions ----
  k_cvt16<<<(256*512+255)/256,256,0,stream>>>(m_down_w,  m_down_w16,  256*512);
  k_cvt16<<<(768*256+255)/256,256,0,stream>>>(ffn_up_w,  ffn_up_w16,  768*256);
  k_cvt16<<<(256*384+255)/256,256,0,stream>>>(ffn_down_w,ffn_down_w16,256*384);
  k_cvt16<<<(512*1024+255)/256,256,0,stream>>>(out_w1,   out_w1_16,   512*1024);
  k_cvt16<<<(256*512+255)/256,256,0,stream>>>(out_w2,    out_w2_16,   256*512);
  k_cvtsplit<<<(1024*256+255)/256,256,0,stream>>>(m_up_w, m_up_whi, m_up_wlo, 1024*256);
  k_wtrans<<<(16*64*64)/256,256,0,stream>>>(s_gate_w, gwT);
  k_wfrag<<<65536/256,256,0,stream>>>(s_rec_w, wfrag);

  // ---- embeddings (+LN0 -> split bf16) ----
  k_embed<<<NP_,256,0,stream>>>(questions,responses,skills,q_embed,qa_embed,
      q_embed_diff,qa_embed_diff,difficult_param, ln0_w, x,qe, h_hi,h_lo, pide,tgt,qsh);
  // ---- block M ----
  k_gemm16s<<<dim3(1024/64,NP_/64),256,0,stream>>>(h_hi,h_lo, m_up_whi,m_up_wlo, m_up_b, A, 1024,256);
  k_conv_silu<<<(NP_*512)/256,256,0,stream>>>(A,1024, m_conv_w,m_conv_b, Bb,512,512);
  k_headwise<<<(NP_*512)/256,256,0,stream>>>(Bb, A,1024, m_q_w,m_k_w,m_v_w, Cb,Db,Eb);
  k_igfg<<<NROW,256,0,stream>>>(Cb,Db,Eb, m_ig_w,m_ig_b,m_fg_w,m_fg_b, igb,fgb);
  k_decay<<<64,256,0,stream>>>(igb,fgb, cs1,gdec,Mrun);
  k_attn<<<dim3((S_+TQ-1)/TQ, B_*NH_),256,0,stream>>>(Cb,Db,Eb, cs1,gdec,Mrun, m_outnorm_w, A);
  k_hout<<<(NP_*512)/256,256,0,stream>>>(A, Bb, m_skip, hout16);
  k_gemm16<<<dim3(256/64,NP_/64),256,0,stream>>>(hout16, m_down_w16, m_down_b, x, x, (bf16*)nullptr, 256,512,0);
  // ---- block S ----
  k_ln<<<NP_,256,0,stream>>>(x, ln1_w, h);
  k_conv_silu<<<(NP_*256)/256,256,0,stream>>>(h,256, s_conv_w,s_conv_b, Bb,256,256);
  k_wx<<<dim3(128,4),256,0,stream>>>(h, Bb, gwT, s_bias, A);
  k_scan<<<64,64,0,stream>>>(A, wfrag, Cb);
  k_ynadd_ln2<<<NP_,256,0,stream>>>(Cb, s_gn_w, x, ln2_w, h16);
  // ---- FFN ----
  k_gemm16<<<dim3(768/64,NP_/64),256,0,stream>>>(h16, ffn_up_w16, ffn_up_b, (const float*)nullptr, A, (bf16*)nullptr, 768,256,0);
  k_ffmul<<<(NP_*384)/256,256,0,stream>>>(A, ffg16);
  k_gemm16<<<dim3(256/64,NP_/64),256,0,stream>>>(ffg16, ffn_down_w16, ffn_down_b, x, x, (bf16*)nullptr, 256,384,0);
  // ---- output head ----
  k_cq_ln<<<NP_,256,0,stream>>>(x, postnorm_w, qe, pide, tgt, cq16);
  k_gemm16<<<dim3(512/64,NP_/64),256,0,stream>>>(cq16, out_w1_16, out_b1, (const float*)nullptr, (float*)nullptr, b16, 512,1024,1);
  k_gemm16<<<dim3(256/64,NP_/64),256,0,stream>>>(b16, out_w2_16, out_b2, (const float*)nullptr, t256, (bf16*)nullptr, 256,512,1);
  k_final<<<NROW,256,0,stream>>>(t256, out_w3, out_b3, qsh, (float*)d_out);
}